// Round 8
// baseline (38.411 us; speedup 1.0000x reference)
//
#include <hip/hip_runtime.h>

#define U 128
#define NSEG 32
#define NPATH 512
#define ROW (NSEG * U)   // 4096 floats per batch row
#define NW 8             // waves per tp block (512 threads)

// Path metadata, grouped (order-preserving) by pout.
struct Meta { unsigned pp; float c; };   // pp = p0 | (p1 << 16)
struct WS {
    Meta meta[NPATH];        // 4096 B
    int  segstart[NSEG + 1]; // CSR boundaries into meta[]
    int  wsplit[NW + 1];     // segment-boundary split per wave
};

// One block, 512 threads: thread k owns path k. Deterministic parallel
// counting-sort by pout (original-k order preserved within each segment).
__global__ __launch_bounds__(512) void build_csr(const float* __restrict__ coeffs,
                                                 const int* __restrict__ p0,
                                                 const int* __restrict__ p1,
                                                 const int* __restrict__ pout,
                                                 WS* __restrict__ ws) {
    __shared__ int wcnt[NPATH / 64][NSEG];   // per-wave per-segment counts
    __shared__ int wpre[NPATH / 64][NSEG];   // prefix over earlier waves
    __shared__ int sseg[NSEG + 1];
    __shared__ int stot[NSEG];

    const int k    = threadIdx.x;
    const int lane = k & 63;
    const int wave = k >> 6;

    const int   po = pout[k];
    const int   a0 = p0[k];
    const int   a1 = p1[k];
    const float c  = coeffs[k];

    // rank within wave + per-wave counts, via 32 ballots
    const unsigned long long lt = (1ull << lane) - 1ull;
    int rank = 0;
    #pragma unroll
    for (int s = 0; s < NSEG; ++s) {
        unsigned long long m = __ballot(po == s);
        if (po == s)  rank = (int)__popcll(m & lt);
        if (lane == s) wcnt[wave][s] = (int)__popcll(m);
    }
    __syncthreads();

    // per-segment: prefix over waves + totals (threads 0..31)
    if (k < NSEG) {
        int tot = 0;
        #pragma unroll
        for (int w = 0; w < NPATH / 64; ++w) { wpre[w][k] = tot; tot += wcnt[w][k]; }
        stot[k] = tot;
    }
    __syncthreads();

    // exclusive scan of totals over segments (wave 0)
    if (k < 64) {
        int v = (k < NSEG) ? stot[k] : 0;
        int inc = v;
        #pragma unroll
        for (int d = 1; d < 64; d <<= 1) {
            int t = __shfl_up(inc, d, 64);
            if (k >= d) inc += t;
        }
        int excl = inc - v;
        if (k < NSEG) sseg[k] = excl;
        if (k == NSEG - 1) sseg[NSEG] = excl + v;
    }
    __syncthreads();

    // scatter (deterministic position)
    {
        Meta m;
        m.pp = (unsigned)a0 | ((unsigned)a1 << 16);
        m.c  = c;
        ws->meta[sseg[po] + wpre[wave][po] + rank] = m;
    }
    if (k <= NSEG) ws->segstart[k] = sseg[k];

    // balanced NW-way split boundaries (wave 0); argmin |segstart - target|
    if (k < 64) {
        #pragma unroll
        for (int w = 1; w < NW; ++w) {
            const int target = (NPATH * w) / NW;
            int key;
            if (k <= NSEG) {
                int d = sseg[k] - target; if (d < 0) d = -d;
                key = (d << 6) | k;
            } else key = 0x7fffffff;
            #pragma unroll
            for (int m = 32; m >= 1; m >>= 1) {
                int o = __shfl_xor(key, m, 64);
                key = (o < key) ? o : key;
            }
            if (k == 0) ws->wsplit[w] = key & 63;
        }
        if (k == 0) { ws->wsplit[0] = 0; ws->wsplit[NW] = NSEG; }
    }
}

// One block (512 threads, 8 waves) per batch row. PIPE-SPLIT operands:
// x0 segments from LDS (ds_read_b128), x1 segments from GLOBAL (L1/L2-
// resident: each block re-reads only its own 16 KiB row). Pair scheme:
// lanes 0-31 path j, lanes 32-63 path j+1, one float4 per lane.
__global__ __launch_bounds__(512) void tp_kernel(const float* __restrict__ x0,
                                                 const float* __restrict__ x1,
                                                 const WS* __restrict__ ws,
                                                 float* __restrict__ out) {
    __shared__ __align__(16) float lds0[ROW];   // 16 KiB: x0 row only
    __shared__ Meta smeta[NPATH];
    __shared__ int  sseg[NSEG + 1];
    __shared__ int  ssplit[NW + 1];

    const int b   = blockIdx.x;
    const int tid = threadIdx.x;

    // stage x0 row (coalesced float4)
    const float4* g0 = reinterpret_cast<const float4*>(x0 + (size_t)b * ROW);
    float4* s0v = reinterpret_cast<float4*>(lds0);
    #pragma unroll
    for (int j = 0; j < (ROW / 4) / 512; ++j)   // 2 iters
        s0v[tid + j * 512] = g0[tid + j * 512];
    if (tid < NPATH / 2)   // 4 KiB of metadata as float4
        reinterpret_cast<float4*>(smeta)[tid] =
            reinterpret_cast<const float4*>(ws->meta)[tid];
    if (tid < NSEG + 1) sseg[tid] = ws->segstart[tid];
    if (tid < NW + 1)   ssplit[tid] = ws->wsplit[tid];
    __syncthreads();

    const int wave = tid >> 6;
    const int lane = tid & 63;
    const int half = lane >> 5;   // 0: low 32 lanes, 1: high 32 lanes
    const int sub  = lane & 31;   // float4 slot within a segment

    const int sBeg = __builtin_amdgcn_readfirstlane(ssplit[wave]);
    const int sEnd = __builtin_amdgcn_readfirstlane(ssplit[wave + 1]);

    const float4* s0q = reinterpret_cast<const float4*>(lds0);
    const float4* x1g = reinterpret_cast<const float4*>(x1 + (size_t)b * ROW);
    float* outrow = out + (size_t)b * ROW;

    for (int s = sBeg; s < sEnd; ++s) {
        const int jb = __builtin_amdgcn_readfirstlane(sseg[s]);
        const int je = __builtin_amdgcn_readfirstlane(sseg[s + 1]);
        float4 acc0 = make_float4(0.f, 0.f, 0.f, 0.f);
        float4 acc1 = make_float4(0.f, 0.f, 0.f, 0.f);
        int j = jb;
        for (; j + 3 < je; j += 4) {   // 4 paths in flight
            const Meta mA = smeta[j + half];
            const Meta mB = smeta[j + 2 + half];
            const float4 wA = x1g[(mA.pp >> 16)     * (U / 4) + sub];  // global (L1/L2)
            const float4 wB = x1g[(mB.pp >> 16)     * (U / 4) + sub];
            const float4 uA = s0q[(mA.pp & 0xffffu) * (U / 4) + sub];  // LDS
            const float4 uB = s0q[(mB.pp & 0xffffu) * (U / 4) + sub];
            acc0.x += mA.c * uA.x * wA.x;
            acc0.y += mA.c * uA.y * wA.y;
            acc0.z += mA.c * uA.z * wA.z;
            acc0.w += mA.c * uA.w * wA.w;
            acc1.x += mB.c * uB.x * wB.x;
            acc1.y += mB.c * uB.y * wB.y;
            acc1.z += mB.c * uB.z * wB.z;
            acc1.w += mB.c * uB.w * wB.w;
        }
        for (; j + 1 < je; j += 2) {   // 2-path tail
            const Meta m = smeta[j + half];
            const float4 w = x1g[(m.pp >> 16)     * (U / 4) + sub];
            const float4 u = s0q[(m.pp & 0xffffu) * (U / 4) + sub];
            acc0.x += m.c * u.x * w.x;
            acc0.y += m.c * u.y * w.y;
            acc0.z += m.c * u.z * w.z;
            acc0.w += m.c * u.w * w.w;
        }
        if (j < je) {                  // odd tail: upper half contributes 0
            const Meta m = smeta[j];
            const float cc = (half == 0) ? m.c : 0.f;
            const float4 w = x1g[(m.pp >> 16)     * (U / 4) + sub];
            const float4 u = s0q[(m.pp & 0xffffu) * (U / 4) + sub];
            acc0.x += cc * u.x * w.x;
            acc0.y += cc * u.y * w.y;
            acc0.z += cc * u.z * w.z;
            acc0.w += cc * u.w * w.w;
        }
        float4 a;
        a.x = acc0.x + acc1.x;
        a.y = acc0.y + acc1.y;
        a.z = acc0.z + acc1.z;
        a.w = acc0.w + acc1.w;
        a.x += __shfl_xor(a.x, 32, 64);
        a.y += __shfl_xor(a.y, 32, 64);
        a.z += __shfl_xor(a.z, 32, 64);
        a.w += __shfl_xor(a.w, 32, 64);
        if (half == 0)
            reinterpret_cast<float4*>(outrow + s * U)[sub] = a;
    }
}

extern "C" void kernel_launch(void* const* d_in, const int* in_sizes, int n_in,
                              void* d_out, int out_size, void* d_ws, size_t ws_size,
                              hipStream_t stream) {
    const float* x0     = (const float*)d_in[0];
    const float* x1     = (const float*)d_in[1];
    const float* coeffs = (const float*)d_in[2];
    const int*   p0     = (const int*)d_in[3];
    const int*   p1     = (const int*)d_in[4];
    const int*   pout   = (const int*)d_in[5];
    float* out = (float*)d_out;
    WS* ws = (WS*)d_ws;

    build_csr<<<1, 512, 0, stream>>>(coeffs, p0, p1, pout, ws);
    tp_kernel<<<2048, 512, 0, stream>>>(x0, x1, ws, out);
}

// Round 9
// 34.741 us; speedup vs baseline: 1.1056x; 1.1056x over previous
//
#include <hip/hip_runtime.h>
#include <hip/hip_fp16.h>

#define U 128
#define NSEG 32
#define NPATH 512
#define ROW (NSEG * U)   // 4096 elements per batch row
#define NW 8             // waves per tp block (512 threads)

// Path metadata, grouped (order-preserving) by pout.
// pp = p0 | (p1 << 16); c2 = bits of half2{c, c}
struct Meta { unsigned pp; unsigned c2; };
struct WS {
    Meta meta[NPATH];        // 4096 B
    int  segstart[NSEG + 1]; // CSR boundaries into meta[]
    int  wsplit[NW + 1];     // segment-boundary split per wave
};

template <typename T, typename F> __device__ inline T bcast(F v) {
    union { F f; T t; } u; u.f = v; return u.t;
}

// One block, 512 threads: thread k owns path k. Deterministic parallel
// counting-sort by pout (original-k order preserved within each segment).
__global__ __launch_bounds__(512) void build_csr(const float* __restrict__ coeffs,
                                                 const int* __restrict__ p0,
                                                 const int* __restrict__ p1,
                                                 const int* __restrict__ pout,
                                                 WS* __restrict__ ws) {
    __shared__ int wcnt[NPATH / 64][NSEG];   // per-wave per-segment counts
    __shared__ int wpre[NPATH / 64][NSEG];   // prefix over earlier waves
    __shared__ int sseg[NSEG + 1];
    __shared__ int stot[NSEG];

    const int k    = threadIdx.x;
    const int lane = k & 63;
    const int wave = k >> 6;

    const int   po = pout[k];
    const int   a0 = p0[k];
    const int   a1 = p1[k];
    const float c  = coeffs[k];

    // rank within wave + per-wave counts, via 32 ballots
    const unsigned long long lt = (1ull << lane) - 1ull;
    int rank = 0;
    #pragma unroll
    for (int s = 0; s < NSEG; ++s) {
        unsigned long long m = __ballot(po == s);
        if (po == s)  rank = (int)__popcll(m & lt);
        if (lane == s) wcnt[wave][s] = (int)__popcll(m);
    }
    __syncthreads();

    // per-segment: prefix over waves + totals (threads 0..31)
    if (k < NSEG) {
        int tot = 0;
        #pragma unroll
        for (int w = 0; w < NPATH / 64; ++w) { wpre[w][k] = tot; tot += wcnt[w][k]; }
        stot[k] = tot;
    }
    __syncthreads();

    // exclusive scan of totals over segments (wave 0)
    if (k < 64) {
        int v = (k < NSEG) ? stot[k] : 0;
        int inc = v;
        #pragma unroll
        for (int d = 1; d < 64; d <<= 1) {
            int t = __shfl_up(inc, d, 64);
            if (k >= d) inc += t;
        }
        int excl = inc - v;
        if (k < NSEG) sseg[k] = excl;
        if (k == NSEG - 1) sseg[NSEG] = excl + v;
    }
    __syncthreads();

    // scatter (deterministic position)
    {
        const __half   h  = __float2half_rn(c);
        const __half2  h2 = __halves2half2(h, h);
        Meta m;
        m.pp = (unsigned)a0 | ((unsigned)a1 << 16);
        m.c2 = bcast<unsigned>(h2);
        ws->meta[sseg[po] + wpre[wave][po] + rank] = m;
    }
    if (k <= NSEG) ws->segstart[k] = sseg[k];

    // balanced NW-way split boundaries (wave 0); argmin |segstart - target|
    if (k < 64) {
        #pragma unroll
        for (int w = 1; w < NW; ++w) {
            const int target = (NPATH * w) / NW;
            int key;
            if (k <= NSEG) {
                int d = sseg[k] - target; if (d < 0) d = -d;
                key = (d << 6) | k;
            } else key = 0x7fffffff;
            #pragma unroll
            for (int m = 32; m >= 1; m >>= 1) {
                int o = __shfl_xor(key, m, 64);
                key = (o < key) ? o : key;
            }
            if (k == 0) ws->wsplit[w] = key & 63;
        }
        if (k == 0) { ws->wsplit[0] = 0; ws->wsplit[NW] = NSEG; }
    }
}

// One block (512 threads, 8 waves) per batch row. Rows staged in LDS as F16
// (16 KiB; cvt_pkrtz during staging). Pair scheme: lanes 0-31 path j,
// lanes 32-63 path j+1, each lane 4 elements via ds_read_b64. Math: packed
// f16 (v_pk_mul + v_pk_fma, coeff pre-packed as half2). f32 convert at
// segment end; cross-half shfl reduce; float4 stores.
__global__ __launch_bounds__(512) void tp_kernel(const float* __restrict__ x0,
                                                 const float* __restrict__ x1,
                                                 const WS* __restrict__ ws,
                                                 float* __restrict__ out) {
    __shared__ __align__(16) __half xh[2 * ROW];   // x0 at [0,ROW), x1 at [ROW,2*ROW)
    __shared__ Meta smeta[NPATH];
    __shared__ int  sseg[NSEG + 1];
    __shared__ int  ssplit[NW + 1];

    const int b   = blockIdx.x;
    const int tid = threadIdx.x;

    // stage + convert rows (coalesced float4 in, uint2 (4×f16) to LDS)
    {
        const float4* g0 = reinterpret_cast<const float4*>(x0 + (size_t)b * ROW);
        const float4* g1 = reinterpret_cast<const float4*>(x1 + (size_t)b * ROW);
        #pragma unroll
        for (int j = 0; j < (ROW / 4) / 512; ++j) {   // 2 iters each
            const int e = tid + j * 512;              // float4 index
            const float4 v0 = g0[e];
            const float4 v1 = g1[e];
            uint2 h0, h1;
            h0.x = bcast<unsigned>(__float22half2_rn(make_float2(v0.x, v0.y)));
            h0.y = bcast<unsigned>(__float22half2_rn(make_float2(v0.z, v0.w)));
            h1.x = bcast<unsigned>(__float22half2_rn(make_float2(v1.x, v1.y)));
            h1.y = bcast<unsigned>(__float22half2_rn(make_float2(v1.z, v1.w)));
            *reinterpret_cast<uint2*>(&xh[e * 4])       = h0;
            *reinterpret_cast<uint2*>(&xh[ROW + e * 4]) = h1;
        }
    }
    if (tid < NPATH / 2)   // 4 KiB of metadata as float4
        reinterpret_cast<float4*>(smeta)[tid] =
            reinterpret_cast<const float4*>(ws->meta)[tid];
    if (tid < NSEG + 1) sseg[tid] = ws->segstart[tid];
    if (tid < NW + 1)   ssplit[tid] = ws->wsplit[tid];
    __syncthreads();

    const int wave = tid >> 6;
    const int lane = tid & 63;
    const int half = lane >> 5;   // 0: low 32 lanes (path j), 1: high (path j+1)
    const int sub  = lane & 31;   // 4-element slot within a segment

    const int sBeg = __builtin_amdgcn_readfirstlane(ssplit[wave]);
    const int sEnd = __builtin_amdgcn_readfirstlane(ssplit[wave + 1]);

    float* outrow = out + (size_t)b * ROW;
    const __half2 zero2 = __halves2half2(__float2half_rn(0.f), __float2half_rn(0.f));

    for (int s = sBeg; s < sEnd; ++s) {
        const int jb = __builtin_amdgcn_readfirstlane(sseg[s]);
        const int je = __builtin_amdgcn_readfirstlane(sseg[s + 1]);
        __half2 aA0 = zero2, aA1 = zero2;   // accumulator pair (4 elems), group A
        __half2 aB0 = zero2, aB1 = zero2;   // group B (unrolled)
        int j = jb;
        for (; j + 3 < je; j += 4) {   // 4 paths in flight
            const Meta mA = smeta[j + half];
            const Meta mB = smeta[j + 2 + half];
            const int oA0 = (int)(mA.pp & 0xffffu) << 7;
            const int oA1 = (int)(mA.pp >> 16)     << 7;
            const int oB0 = (int)(mB.pp & 0xffffu) << 7;
            const int oB1 = (int)(mB.pp >> 16)     << 7;
            const uint2 uA = *reinterpret_cast<const uint2*>(&xh[oA0 + sub * 4]);
            const uint2 wA = *reinterpret_cast<const uint2*>(&xh[ROW + oA1 + sub * 4]);
            const uint2 uB = *reinterpret_cast<const uint2*>(&xh[oB0 + sub * 4]);
            const uint2 wB = *reinterpret_cast<const uint2*>(&xh[ROW + oB1 + sub * 4]);
            const __half2 cA = bcast<__half2>(mA.c2);
            const __half2 cB = bcast<__half2>(mB.c2);
            aA0 = __hfma2(__hmul2(bcast<__half2>(uA.x), bcast<__half2>(wA.x)), cA, aA0);
            aA1 = __hfma2(__hmul2(bcast<__half2>(uA.y), bcast<__half2>(wA.y)), cA, aA1);
            aB0 = __hfma2(__hmul2(bcast<__half2>(uB.x), bcast<__half2>(wB.x)), cB, aB0);
            aB1 = __hfma2(__hmul2(bcast<__half2>(uB.y), bcast<__half2>(wB.y)), cB, aB1);
        }
        for (; j + 1 < je; j += 2) {   // 2-path tail
            const Meta m = smeta[j + half];
            const int o0 = (int)(m.pp & 0xffffu) << 7;
            const int o1 = (int)(m.pp >> 16)     << 7;
            const uint2 u = *reinterpret_cast<const uint2*>(&xh[o0 + sub * 4]);
            const uint2 w = *reinterpret_cast<const uint2*>(&xh[ROW + o1 + sub * 4]);
            const __half2 c = bcast<__half2>(m.c2);
            aA0 = __hfma2(__hmul2(bcast<__half2>(u.x), bcast<__half2>(w.x)), c, aA0);
            aA1 = __hfma2(__hmul2(bcast<__half2>(u.y), bcast<__half2>(w.y)), c, aA1);
        }
        if (j < je) {                  // odd tail: upper half contributes 0
            const Meta m = smeta[j];
            const int o0 = (int)(m.pp & 0xffffu) << 7;
            const int o1 = (int)(m.pp >> 16)     << 7;
            const uint2 u = *reinterpret_cast<const uint2*>(&xh[o0 + sub * 4]);
            const uint2 w = *reinterpret_cast<const uint2*>(&xh[ROW + o1 + sub * 4]);
            const __half2 c = (half == 0) ? bcast<__half2>(m.c2) : zero2;
            aA0 = __hfma2(__hmul2(bcast<__half2>(u.x), bcast<__half2>(w.x)), c, aA0);
            aA1 = __hfma2(__hmul2(bcast<__half2>(u.y), bcast<__half2>(w.y)), c, aA1);
        }
        // combine unroll groups + convert to f32
        const float2 f0a = __half22float2(aA0), f0b = __half22float2(aB0);
        const float2 f1a = __half22float2(aA1), f1b = __half22float2(aB1);
        float4 a;
        a.x = f0a.x + f0b.x;
        a.y = f0a.y + f0b.y;
        a.z = f1a.x + f1b.x;
        a.w = f1a.y + f1b.y;
        // cross-half reduce (path j + path j+1)
        a.x += __shfl_xor(a.x, 32, 64);
        a.y += __shfl_xor(a.y, 32, 64);
        a.z += __shfl_xor(a.z, 32, 64);
        a.w += __shfl_xor(a.w, 32, 64);
        if (half == 0)
            reinterpret_cast<float4*>(outrow + s * U)[sub] = a;
    }
}

extern "C" void kernel_launch(void* const* d_in, const int* in_sizes, int n_in,
                              void* d_out, int out_size, void* d_ws, size_t ws_size,
                              hipStream_t stream) {
    const float* x0     = (const float*)d_in[0];
    const float* x1     = (const float*)d_in[1];
    const float* coeffs = (const float*)d_in[2];
    const int*   p0     = (const int*)d_in[3];
    const int*   p1     = (const int*)d_in[4];
    const int*   pout   = (const int*)d_in[5];
    float* out = (float*)d_out;
    WS* ws = (WS*)d_ws;

    build_csr<<<1, 512, 0, stream>>>(coeffs, p0, p1, pout, ws);
    tp_kernel<<<2048, 512, 0, stream>>>(x0, x1, ws, out);
}